// Round 4
// baseline (149.637 us; speedup 1.0000x reference)
//
#include <hip/hip_runtime.h>
#include <hip/hip_bf16.h>
#include <math.h>

// ---------------------------------------------------------------------------
// PointerNet attention scorer, MI355X / gfx950.
// Pipeline:
//   1) convert_hilo: fp32 -> bf16 hi/lo planes (row: [hi 512 | lo 512])
//   2) proj_gemm:    C = scale*(A@W^T + bias), bf16 MFMA, 3-pass hi/lo
//      (hiA*hiW + hiA*loW + loA*hiW, rel err ~2^-16), register-prefetch
//      double buffering, ds_write staging (NO global_load_lds), 384 blocks.
//      src -> spq h-quad-interleaved; query -> qp row-major.
//   3) attn_score:   logit ~ -2*sum_h w2/(exp2(sp'+qp')+1)  (shift-invariant
//      terms dropped), masked softmax over S.
// ---------------------------------------------------------------------------

#define TANH_PRESCALE 2.8853900817779268f   // 2*log2(e)
#define LOG2E        1.4426950408889634f

typedef __attribute__((ext_vector_type(8))) short short8;   // 8 bf16 = 4 VGPR
typedef __attribute__((ext_vector_type(4))) float f32x4;    // MFMA C/D frag

__device__ __forceinline__ float fast_exp2(float x) {
#if __has_builtin(__builtin_amdgcn_exp2f)
    return __builtin_amdgcn_exp2f(x);
#else
    return exp2f(x);
#endif
}
__device__ __forceinline__ float fast_rcp(float x) {
#if __has_builtin(__builtin_amdgcn_rcpf)
    return __builtin_amdgcn_rcpf(x);
#else
    return 1.0f / x;
#endif
}
__device__ __forceinline__ float hi_part(float x) {   // truncate to bf16 grid
    return __uint_as_float(__float_as_uint(x) & 0xffff0000u);
}
// pack bf16(a)=low16, bf16(b)=high16 (truncating) in one v_perm
__device__ __forceinline__ unsigned pack2(float a, float b) {
    return __builtin_amdgcn_perm(__float_as_uint(b), __float_as_uint(a), 0x07060302u);
}

// ---------------------------------------------------------------------------
// 1) fp32 -> bf16 hi/lo. Out row (1024 ushorts): [hi k=0..511 | lo k=0..511]
// blocks: 0..511 src(4096r), 512..767 query(2048r, appended to Ah),
//         768..799 W_src(256r), 800..831 W_q(256r). 8 rows/block.
// ---------------------------------------------------------------------------
__global__ __launch_bounds__(256) void convert_hilo(
    const float* __restrict__ src, const float* __restrict__ query,
    const float* __restrict__ Wsrc, const float* __restrict__ Wq,
    unsigned short* __restrict__ Ah, unsigned short* __restrict__ Wsh,
    unsigned short* __restrict__ Wqh)
{
    const int b = blockIdx.x;
    const float* in; unsigned short* out; int r0;
    if (b < 512)      { in = src;   out = Ah;                       r0 = b * 8; }
    else if (b < 768) { in = query; out = Ah + (size_t)4096 * 1024; r0 = (b - 512) * 8; }
    else if (b < 800) { in = Wsrc;  out = Wsh;                      r0 = (b - 768) * 8; }
    else              { in = Wq;    out = Wqh;                      r0 = (b - 800) * 8; }
    in  += (size_t)r0 * 512;
    out += (size_t)r0 * 1024;
    const int tid = threadIdx.x;
    #pragma unroll
    for (int i = 0; i < 4; ++i) {
        const int idx = i * 256 + tid;          // 1024 float4s per block
        const int row = idx >> 7, k4 = idx & 127;
        float4 v = *(const float4*)(in + (size_t)row * 512 + k4 * 4);
        unsigned h0 = pack2(v.x, v.y), h1 = pack2(v.z, v.w);
        float lx = v.x - hi_part(v.x), ly = v.y - hi_part(v.y);
        float lz = v.z - hi_part(v.z), lw = v.w - hi_part(v.w);
        unsigned l0 = pack2(lx, ly), l1 = pack2(lz, lw);
        *(uint2*)(out + (size_t)row * 1024 + k4 * 4)       = make_uint2(h0, h1);
        *(uint2*)(out + (size_t)row * 1024 + 512 + k4 * 4) = make_uint2(l0, l1);
    }
}

// ---------------------------------------------------------------------------
// 2) MFMA GEMM. Tile 128m x 32n, grid 48 x 8 = 384 blocks, 256 thr (4 waves),
// wave = 32m x 32n (2x2 16x16x32 frags). 12 stages of BK=128 bf16:
//   s=2t  (t<4): A_hi(t) * W_hi(t)     s=2t+1 (t<4): A_hi(t) * W_lo(t)
//   s=8+t (t<4): A_lo(t) * W_hi(t)
// A tile reused across each (hi,lo) pair -> staged only when it changes.
// Register-prefetch dbuf: global loads for stage s+1 issued before compute(s).
// LDS pitch 272 B (17x16B) -> b128 reads/writes at the 8-group floor.
// ---------------------------------------------------------------------------
#define PITCH 272
#define WOFF  34816          // A: 128*272 = 34816 ; W: 32*272 = 8704 ; tot 43520

__global__ __launch_bounds__(256) void proj_gemm(
    const unsigned short* __restrict__ Ah,
    const unsigned short* __restrict__ Wsh, const unsigned short* __restrict__ Wqh,
    const float* __restrict__ b_src, const float* __restrict__ b_q,
    float* __restrict__ spq, float* __restrict__ qp)
{
    const int bx = blockIdx.x;       // 0..47 (0..31 src, 32..47 query)
    const int nb = blockIdx.y;       // 0..7
    const bool isSrc = bx < 32;
    const int mrow0 = (isSrc ? bx : bx - 32) * 128;
    const size_t arow0 = isSrc ? (size_t)bx * 128
                               : (size_t)(4096 + (bx - 32) * 128);
    const unsigned short* Wm = isSrc ? Wsh : Wqh;
    const float* bias = isSrc ? b_src : b_q;

    __shared__ char LB[43520];

    const int tid  = threadIdx.x;
    const int lane = tid & 63;
    const int wv   = tid >> 6;        // 0..3 -> m offset wv*32
    const int l15  = lane & 15;
    const int q4   = lane >> 4;       // 0..3

    const int srow = tid >> 4;        // 0..15 staging row base
    const int soct = tid & 15;        // 16B octet within 256B k-row
    const char* Agb = (const char*)(Ah + arow0 * 1024);
    const char* Wgb = (const char*)(Wm + (size_t)(nb * 32) * 1024);

    // stage tables (ushort k-offsets into the 1024-wide hi|lo row)
    //   needA(s): A tile changes (s even, or s>=8)
    #define KA(s) (((s) < 8) ? (((s) >> 1) * 128) : (512 + ((s) - 8) * 128))
    #define KW(s) (((s) < 8) ? ((((s) & 1) * 512) + (((s) >> 1) * 128)) \
                             : (((s) - 8) * 128))
    #define NEEDA(s) (!(((s) < 8) && (((s) & 1))))

    uint4 pa[8], pw[2];
    #define LOADA(s) { const char* g = Agb + (size_t)KA(s) * 2 + soct * 16;      \
        _Pragma("unroll") for (int p = 0; p < 8; ++p)                            \
            pa[p] = *(const uint4*)(g + (size_t)(srow + 16 * p) * 2048); }
    #define LOADW(s) { const char* g = Wgb + (size_t)KW(s) * 2 + soct * 16;      \
        _Pragma("unroll") for (int p = 0; p < 2; ++p)                            \
            pw[p] = *(const uint4*)(g + (size_t)(srow + 16 * p) * 2048); }

    f32x4 acc[2][2];
    #pragma unroll
    for (int i = 0; i < 2; ++i)
        #pragma unroll
        for (int j = 0; j < 2; ++j) acc[i][j] = (f32x4){0.f, 0.f, 0.f, 0.f};

    LOADA(0) LOADW(0)
    #pragma unroll 1
    for (int s = 0; s < 12; ++s) {
        __syncthreads();                       // LDS free (prev compute done)
        if (NEEDA(s)) {
            #pragma unroll
            for (int p = 0; p < 8; ++p)
                *(uint4*)(LB + (srow + 16 * p) * PITCH + soct * 16) = pa[p];
        }
        #pragma unroll
        for (int p = 0; p < 2; ++p)
            *(uint4*)(LB + WOFF + (srow + 16 * p) * PITCH + soct * 16) = pw[p];
        __syncthreads();                       // staged
        if (s + 1 < 12) {                      // prefetch next stage into regs
            if (NEEDA(s + 1)) LOADA(s + 1)
            LOADW(s + 1)
        }
        #pragma unroll
        for (int kk = 0; kk < 4; ++kk) {
            const int o = kk * 4 + q4;         // 16B octet 0..15 (k sub-range)
            short8 a0 = *(const short8*)(LB + (wv * 32 + l15)      * PITCH + o * 16);
            short8 a1 = *(const short8*)(LB + (wv * 32 + 16 + l15) * PITCH + o * 16);
            short8 w0 = *(const short8*)(LB + WOFF + (l15)      * PITCH + o * 16);
            short8 w1 = *(const short8*)(LB + WOFF + (16 + l15) * PITCH + o * 16);
            acc[0][0] = __builtin_amdgcn_mfma_f32_16x16x32_bf16(a0, w0, acc[0][0], 0, 0, 0);
            acc[0][1] = __builtin_amdgcn_mfma_f32_16x16x32_bf16(a0, w1, acc[0][1], 0, 0, 0);
            acc[1][0] = __builtin_amdgcn_mfma_f32_16x16x32_bf16(a1, w0, acc[1][0], 0, 0, 0);
            acc[1][1] = __builtin_amdgcn_mfma_f32_16x16x32_bf16(a1, w1, acc[1][1], 0, 0, 0);
        }
    }

    float bl[2];
    #pragma unroll
    for (int ni = 0; ni < 2; ++ni) bl[ni] = bias[nb * 32 + ni * 16 + l15];

    __syncthreads();                 // frag reads done before E overwrites LDS
    float* E = (float*)LB;           // 128 x 36 fp32 = 18432 B
    #pragma unroll
    for (int mi = 0; mi < 2; ++mi)
        #pragma unroll
        for (int ni = 0; ni < 2; ++ni) {
            const int m = wv * 32 + mi * 16 + q4 * 4;   // C/D: row=(lane>>4)*4+r
            const int n = ni * 16 + l15;                //      col=lane&15
            #pragma unroll
            for (int r = 0; r < 4; ++r)
                E[(m + r) * 36 + n] = (acc[mi][ni][r] + bl[ni]) * TANH_PRESCALE;
        }
    __syncthreads();

    if (isSrc) {   // h-quad-interleaved: spq[(nb*8+nq)*16384 + (mrow0+m)*4 + (n&3)]
        const int nq = tid >> 5;                     // 0..7
        #pragma unroll
        for (int j = 0; j < 4; ++j) {
            const int m = (tid & 31) + 32 * j;       // 0..127
            float4 v = *(const float4*)&E[m * 36 + nq * 4];
            *(float4*)(spq + (size_t)(nb * 8 + nq) * 16384
                           + (size_t)(mrow0 + m) * 4) = v;
        }
    } else {       // row-major qp[(mrow0+m)*256 + nb*32 + n]
        #pragma unroll
        for (int p = 0; p < 4; ++p) {
            const int m = (tid >> 3) + 32 * p;       // 0..127
            const int c = tid & 7;
            float4 v = *(const float4*)&E[m * 36 + c * 4];
            *(float4*)(qp + (size_t)(mrow0 + m) * 256 + nb * 32 + c * 4) = v;
        }
    }
}

// ---------------------------------------------------------------------------
// 3) Fused score + masked softmax. Block = (b, 4-t chunk), 512 thr (8 waves).
// Thread (s, h-group g of 64) carries 4 t-accumulators; 1-deep manual global
// prefetch on the strided spq loads; partials combined in LDS; per-wave
// softmax over S=128 in waves 0..3. Mask preloaded at kernel top.
// ---------------------------------------------------------------------------
__global__ __launch_bounds__(512) void attn_score(
    const float* __restrict__ spq, const float* __restrict__ qp,
    const float* __restrict__ w2, const int* __restrict__ mask,
    float* __restrict__ out)
{
    const int b  = blockIdx.x;   // 0..31
    const int tz = blockIdx.y;   // 0..15
    const int tid = threadIdx.x;

    __shared__ float qp_s[4][256];
    __shared__ float w2_s[256];
    __shared__ float h2p[4][4][128];   // [h-group][t-local][s]

    int mk0 = 0, mk1 = 0;
    if (tid < 256) {
        const int tl = tid >> 6, lane = tid & 63;
        const int t = tz * 4 + tl;
        *(float4*)&qp_s[tl][lane * 4] =
            *(const float4*)(qp + (size_t)(t * 32 + b) * 256 + lane * 4);
        mk0 = mask[b * 128 + lane];            // preload mask (used post-loop)
        mk1 = mask[b * 128 + lane + 64];
    } else if (tid < 320) {
        const int i = tid - 256;
        *(float4*)&w2_s[i * 4] = *(const float4*)(w2 + i * 4);
    }
    __syncthreads();

    const int s = tid & 127;
    const int g = tid >> 7;            // 0..3 -> h in [g*64, g*64+64)
    const int hb = g * 64;
    const float* sq = spq + (size_t)(g * 16) * 16384 + (size_t)(b * 128 + s) * 4;

    float acc0 = 0.f, acc1 = 0.f, acc2 = 0.f, acc3 = 0.f;
    float4 s4 = *(const float4*)sq;                 // prefetch hq=0
    #pragma unroll 4
    for (int hq = 0; hq < 16; ++hq) {
        float4 nxt;
        if (hq < 15) nxt = *(const float4*)(sq + (size_t)(hq + 1) * 16384);
        float4 w4 = *(const float4*)&w2_s[hb + hq * 4];
        float4 q0 = *(const float4*)&qp_s[0][hb + hq * 4];
        float4 q1 = *(const float4*)&qp_s[1][hb + hq * 4];
        float4 q2 = *(const float4*)&qp_s[2][hb + hq * 4];
        float4 q3 = *(const float4*)&qp_s[3][hb + hq * 4];
        #define PN_TERM(sj, wj, q0j, q1j, q2j, q3j)                              \
            { float r;                                                           \
              r = fast_rcp(fast_exp2(sj + q0j) + 1.0f); acc0 = fmaf(wj, r, acc0);\
              r = fast_rcp(fast_exp2(sj + q1j) + 1.0f); acc1 = fmaf(wj, r, acc1);\
              r = fast_rcp(fast_exp2(sj + q2j) + 1.0f); acc2 = fmaf(wj, r, acc2);\
              r = fast_rcp(fast_exp2(sj + q3j) + 1.0f); acc3 = fmaf(wj, r, acc3); }
        PN_TERM(s4.x, w4.x, q0.x, q1.x, q2.x, q3.x)
        PN_TERM(s4.y, w4.y, q0.y, q1.y, q2.y, q3.y)
        PN_TERM(s4.z, w4.z, q0.z, q1.z, q2.z, q3.z)
        PN_TERM(s4.w, w4.w, q0.w, q1.w, q2.w, q3.w)
        #undef PN_TERM
        s4 = nxt;
    }
    h2p[g][0][s] = acc0;
    h2p[g][1][s] = acc1;
    h2p[g][2][s] = acc2;
    h2p[g][3][s] = acc3;
    __syncthreads();

    if (tid < 256) {
        const int wv = tid >> 6, lane = tid & 63;
        float v0 = -2.0f * (h2p[0][wv][lane] + h2p[1][wv][lane]
                          + h2p[2][wv][lane] + h2p[3][wv][lane]);
        float v1 = -2.0f * (h2p[0][wv][lane + 64] + h2p[1][wv][lane + 64]
                          + h2p[2][wv][lane + 64] + h2p[3][wv][lane + 64]);
        if (mk0) v0 = -__builtin_inff();
        if (mk1) v1 = -__builtin_inff();

        float mx = fmaxf(v0, v1);
        #pragma unroll
        for (int off = 32; off >= 1; off >>= 1) mx = fmaxf(mx, __shfl_xor(mx, off));
        float e0 = fast_exp2((v0 - mx) * LOG2E);   // -inf -> 0
        float e1 = fast_exp2((v1 - mx) * LOG2E);
        float sum = e0 + e1;
        #pragma unroll
        for (int off = 32; off >= 1; off >>= 1) sum += __shfl_xor(sum, off);
        const float r = fast_rcp(sum);

        const size_t ob = (size_t)((tz * 4 + wv) * 32 + b) * 128;
        out[ob + lane]      = e0 * r;
        out[ob + lane + 64] = e1 * r;
    }
}

extern "C" void kernel_launch(void* const* d_in, const int* in_sizes, int n_in,
                              void* d_out, int out_size, void* d_ws, size_t ws_size,
                              hipStream_t stream) {
    const float* src   = (const float*)d_in[0];   // (B,S,E)
    const int*   mask  = (const int*)  d_in[1];   // (B,S)
    const float* query = (const float*)d_in[2];   // (T,B,Q)
    const float* W_src = (const float*)d_in[3];   // (H,E)
    const float* b_src = (const float*)d_in[4];
    const float* W_q   = (const float*)d_in[5];   // (H,Q)
    const float* b_q   = (const float*)d_in[6];
    const float* w2    = (const float*)d_in[7];
    // d_in[8] = b2 : unused (softmax shift-invariant)
    float* out = (float*)d_out;

    // ws layout (bytes): spq 0..4MB | qp 4..6MB | Ah 6..18.6MB | Wsh | Wqh
    float* spq = (float*)d_ws;
    float* qp  = (float*)((char*)d_ws + (4u << 20));
    unsigned short* Ah  = (unsigned short*)((char*)d_ws + (6u << 20));
    unsigned short* Wsh = (unsigned short*)((char*)d_ws + 18874368u);
    unsigned short* Wqh = (unsigned short*)((char*)d_ws + 19398656u);

    convert_hilo<<<832, 256, 0, stream>>>(src, query, W_src, W_q, Ah, Wsh, Wqh);
    proj_gemm<<<dim3(48, 8), 256, 0, stream>>>(Ah, Wsh, Wqh, b_src, b_q, spq, qp);
    attn_score<<<dim3(32, 16), 512, 0, stream>>>(spq, qp, w2, mask, out);
}

// Round 5
// 101.221 us; speedup vs baseline: 1.4783x; 1.4783x over previous
//
#include <hip/hip_runtime.h>
#include <hip/hip_bf16.h>
#include <math.h>

// ---------------------------------------------------------------------------
// PointerNet attention scorer, MI355X / gfx950.
//   1) proj_gemm: C = scale*(A@W^T + bias) on bf16 MFMA with in-staging
//      fp32->bf16 hi/lo split (3 passes: hiA*hiW + hiA*loW + loA*hiW,
//      rel err ~2^-16). Tile 64m x 64n, grid (96,4)=384 blocks, 256 thr,
//      single-buffered LDS (R2-proven mechanics; no global_load_lds, no
//      reg-prefetch dbuf — both regressed). src -> spq h-quad-interleaved,
//      query -> qp row-major.
//   2) attn_score: logit ~ -2*sum_h w2[h]/(exp2(sp'+qp')+1) (shift-invariant
//      terms b2 + sum(w2) dropped), masked softmax over S=128.
// ---------------------------------------------------------------------------

#define TANH_PRESCALE 2.8853900817779268f   // 2*log2(e)
#define LOG2E        1.4426950408889634f

typedef __attribute__((ext_vector_type(8))) short short8;   // 8 bf16 = 4 VGPR
typedef __attribute__((ext_vector_type(4))) float f32x4;    // MFMA C/D frag

__device__ __forceinline__ float fast_exp2(float x) {
#if __has_builtin(__builtin_amdgcn_exp2f)
    return __builtin_amdgcn_exp2f(x);
#else
    return exp2f(x);
#endif
}
__device__ __forceinline__ float fast_rcp(float x) {
#if __has_builtin(__builtin_amdgcn_rcpf)
    return __builtin_amdgcn_rcpf(x);
#else
    return 1.0f / x;
#endif
}
__device__ __forceinline__ float hi_part(float x) {   // truncate to bf16 grid
    return __uint_as_float(__float_as_uint(x) & 0xffff0000u);
}
// pack bf16(a)=low16, bf16(b)=high16 (truncating) in one v_perm
__device__ __forceinline__ unsigned pack2(float a, float b) {
    return __builtin_amdgcn_perm(__float_as_uint(b), __float_as_uint(a), 0x07060302u);
}

// ---------------------------------------------------------------------------
// proj_gemm. bx 0..95: bx<64 -> src rows [bx*64, +64); else query rows.
// nb 0..3 -> n in [nb*64, +64). 4 waves; wave wv -> (wm=wv&1, wn=wv>>1),
// wave tile 32m x 32n = 2x2 16x16x32 frags. K-loop: 8 tiles of BK=64 fp32,
// converted to hi/lo bf16 in LDS during staging.
// LDS pitch 72 ushorts (144 B): frag-read bank-quads (row+oct)%8 uniform.
// ---------------------------------------------------------------------------
#define AHI 0
#define ALO 4608            // 64*72
#define WHI 9216
#define WLO 13824
#define LDS_USH 18432       // 36864 B

__global__ __launch_bounds__(256) void proj_gemm(
    const float* __restrict__ src, const float* __restrict__ query,
    const float* __restrict__ Wsrc, const float* __restrict__ Wq,
    const float* __restrict__ b_src, const float* __restrict__ b_q,
    float* __restrict__ spq, float* __restrict__ qp)
{
    const int bx = blockIdx.x;        // 0..95
    const int nb = blockIdx.y;        // 0..3
    const bool isSrc = bx < 64;
    const int mrow0 = (isSrc ? bx : bx - 64) * 64;
    const float* __restrict__ A    = isSrc ? src  : query;
    const float* __restrict__ W    = isSrc ? Wsrc : Wq;
    const float* __restrict__ bias = isSrc ? b_src : b_q;

    __shared__ unsigned short LS[LDS_USH];

    const int tid  = threadIdx.x;
    const int lane = tid & 63;
    const int wv   = tid >> 6;
    const int wm   = wv & 1, wn = wv >> 1;
    const int l15  = lane & 15;
    const int q4   = lane >> 4;       // 0..3

    // staging decomposition: idx = p*256+tid -> row=idx>>3 (0..63), c8=idx&7
    const int srow = tid >> 3;        // rows for p=0 (0..31); p=1 adds 32
    const int sc8  = tid & 7;

    f32x4 acc[2][2];
    #pragma unroll
    for (int i = 0; i < 2; ++i)
        #pragma unroll
        for (int j = 0; j < 2; ++j) acc[i][j] = (f32x4){0.f, 0.f, 0.f, 0.f};

    const float* Ab = A + (size_t)mrow0 * 512 + sc8 * 8;
    const float* Wb = W + (size_t)(nb * 64) * 512 + sc8 * 8;

    for (int kt = 0; kt < 512; kt += 64) {
        __syncthreads();   // previous tile's frag reads done
        #pragma unroll
        for (int p = 0; p < 2; ++p) {          // A: 64 rows x 64 k
            const int row = srow + 32 * p;
            const float* g = Ab + (size_t)row * 512 + kt;
            float4 v0 = *(const float4*)g, v1 = *(const float4*)(g + 4);
            uint4 h; uint4 l;
            h.x = pack2(v0.x, v0.y);  h.y = pack2(v0.z, v0.w);
            h.z = pack2(v1.x, v1.y);  h.w = pack2(v1.z, v1.w);
            l.x = pack2(v0.x - hi_part(v0.x), v0.y - hi_part(v0.y));
            l.y = pack2(v0.z - hi_part(v0.z), v0.w - hi_part(v0.w));
            l.z = pack2(v1.x - hi_part(v1.x), v1.y - hi_part(v1.y));
            l.w = pack2(v1.z - hi_part(v1.z), v1.w - hi_part(v1.w));
            *(uint4*)&LS[AHI + row * 72 + sc8 * 8] = h;
            *(uint4*)&LS[ALO + row * 72 + sc8 * 8] = l;
        }
        #pragma unroll
        for (int p = 0; p < 2; ++p) {          // W: 64 rows x 64 k
            const int row = srow + 32 * p;
            const float* g = Wb + (size_t)row * 512 + kt;
            float4 v0 = *(const float4*)g, v1 = *(const float4*)(g + 4);
            uint4 h; uint4 l;
            h.x = pack2(v0.x, v0.y);  h.y = pack2(v0.z, v0.w);
            h.z = pack2(v1.x, v1.y);  h.w = pack2(v1.z, v1.w);
            l.x = pack2(v0.x - hi_part(v0.x), v0.y - hi_part(v0.y));
            l.y = pack2(v0.z - hi_part(v0.z), v0.w - hi_part(v0.w));
            l.z = pack2(v1.x - hi_part(v1.x), v1.y - hi_part(v1.y));
            l.w = pack2(v1.z - hi_part(v1.z), v1.w - hi_part(v1.w));
            *(uint4*)&LS[WHI + row * 72 + sc8 * 8] = h;
            *(uint4*)&LS[WLO + row * 72 + sc8 * 8] = l;
        }
        __syncthreads();

        #pragma unroll
        for (int pass = 0; pass < 3; ++pass) {
            const unsigned short* Ap = LS + (pass == 2 ? ALO : AHI);
            const unsigned short* Wp = LS + (pass == 1 ? WLO : WHI);
            #pragma unroll
            for (int kk = 0; kk < 2; ++kk) {
                const int off = (kk * 4 + q4) * 8;    // ushort k-octet offset
                short8 a0 = *(const short8*)&Ap[(wm * 32 + l15)      * 72 + off];
                short8 a1 = *(const short8*)&Ap[(wm * 32 + 16 + l15) * 72 + off];
                short8 w0 = *(const short8*)&Wp[(wn * 32 + l15)      * 72 + off];
                short8 w1 = *(const short8*)&Wp[(wn * 32 + 16 + l15) * 72 + off];
                acc[0][0] = __builtin_amdgcn_mfma_f32_16x16x32_bf16(a0, w0, acc[0][0], 0, 0, 0);
                acc[0][1] = __builtin_amdgcn_mfma_f32_16x16x32_bf16(a0, w1, acc[0][1], 0, 0, 0);
                acc[1][0] = __builtin_amdgcn_mfma_f32_16x16x32_bf16(a1, w0, acc[1][0], 0, 0, 0);
                acc[1][1] = __builtin_amdgcn_mfma_f32_16x16x32_bf16(a1, w1, acc[1][1], 0, 0, 0);
            }
        }
    }

    float bl[2];
    #pragma unroll
    for (int ni = 0; ni < 2; ++ni)
        bl[ni] = bias[nb * 64 + wn * 32 + ni * 16 + l15];

    __syncthreads();                 // frag reads done before E overwrites LDS
    float* E = (float*)LS;           // 64 x 68 fp32 = 17408 B
    #pragma unroll
    for (int mi = 0; mi < 2; ++mi)
        #pragma unroll
        for (int ni = 0; ni < 2; ++ni) {
            const int m = wm * 32 + mi * 16 + q4 * 4;   // C/D: row=(lane>>4)*4+r
            const int n = wn * 32 + ni * 16 + l15;      //      col=lane&15
            #pragma unroll
            for (int r = 0; r < 4; ++r)
                E[(m + r) * 68 + n] = (acc[mi][ni][r] + bl[ni]) * TANH_PRESCALE;
        }
    __syncthreads();

    if (isSrc) {
        // h-quad-interleaved: spq[(nb*16+nq)*16384 + (mrow0+m)*4 + (n&3)]
        const int nq = tid >> 4;                     // 0..15
        #pragma unroll
        for (int j = 0; j < 4; ++j) {
            const int m = (tid & 15) + 16 * j;       // 0..63
            float4 v = *(const float4*)&E[m * 68 + nq * 4];
            *(float4*)(spq + (size_t)(nb * 16 + nq) * 16384
                           + (size_t)(mrow0 + m) * 4) = v;
        }
    } else {
        // row-major qp[(mrow0+m)*256 + nb*64 + n]
        #pragma unroll
        for (int p = 0; p < 4; ++p) {
            const int idx = p * 256 + tid;
            const int m = idx >> 4, c4 = idx & 15;
            float4 v = *(const float4*)&E[m * 68 + c4 * 4];
            *(float4*)(qp + (size_t)(mrow0 + m) * 256 + nb * 64 + c4 * 4) = v;
        }
    }
}

// ---------------------------------------------------------------------------
// Fused score + masked softmax. Block = (b, 4-t chunk), 512 thr (8 waves).
// Thread (s, h-group g of 64) carries 4 t-accumulators; 1-deep manual global
// prefetch on strided spq loads; partials combined in LDS; per-wave softmax
// over S=128 in waves 0..3.
// ---------------------------------------------------------------------------
__global__ __launch_bounds__(512) void attn_score(
    const float* __restrict__ spq, const float* __restrict__ qp,
    const float* __restrict__ w2, const int* __restrict__ mask,
    float* __restrict__ out)
{
    const int b  = blockIdx.x;   // 0..31
    const int tz = blockIdx.y;   // 0..15
    const int tid = threadIdx.x;

    __shared__ float qp_s[4][256];
    __shared__ float w2_s[256];
    __shared__ float h2p[4][4][128];   // [h-group][t-local][s]

    int mk0 = 0, mk1 = 0;
    if (tid < 256) {
        const int tl = tid >> 6, lane = tid & 63;
        const int t = tz * 4 + tl;
        *(float4*)&qp_s[tl][lane * 4] =
            *(const float4*)(qp + (size_t)(t * 32 + b) * 256 + lane * 4);
        mk0 = mask[b * 128 + lane];
        mk1 = mask[b * 128 + lane + 64];
    } else if (tid < 320) {
        const int i = tid - 256;
        *(float4*)&w2_s[i * 4] = *(const float4*)(w2 + i * 4);
    }
    __syncthreads();

    const int s = tid & 127;
    const int g = tid >> 7;            // 0..3 -> h in [g*64, g*64+64)
    const int hb = g * 64;
    const float* sq = spq + (size_t)(g * 16) * 16384 + (size_t)(b * 128 + s) * 4;

    float acc0 = 0.f, acc1 = 0.f, acc2 = 0.f, acc3 = 0.f;
    float4 s4 = *(const float4*)sq;                 // prefetch hq=0
    #pragma unroll 4
    for (int hq = 0; hq < 16; ++hq) {
        float4 nxt;
        if (hq < 15) nxt = *(const float4*)(sq + (size_t)(hq + 1) * 16384);
        float4 w4 = *(const float4*)&w2_s[hb + hq * 4];
        float4 q0 = *(const float4*)&qp_s[0][hb + hq * 4];
        float4 q1 = *(const float4*)&qp_s[1][hb + hq * 4];
        float4 q2 = *(const float4*)&qp_s[2][hb + hq * 4];
        float4 q3 = *(const float4*)&qp_s[3][hb + hq * 4];
        #define PN_TERM(sj, wj, q0j, q1j, q2j, q3j)                              \
            { float r;                                                           \
              r = fast_rcp(fast_exp2(sj + q0j) + 1.0f); acc0 = fmaf(wj, r, acc0);\
              r = fast_rcp(fast_exp2(sj + q1j) + 1.0f); acc1 = fmaf(wj, r, acc1);\
              r = fast_rcp(fast_exp2(sj + q2j) + 1.0f); acc2 = fmaf(wj, r, acc2);\
              r = fast_rcp(fast_exp2(sj + q3j) + 1.0f); acc3 = fmaf(wj, r, acc3); }
        PN_TERM(s4.x, w4.x, q0.x, q1.x, q2.x, q3.x)
        PN_TERM(s4.y, w4.y, q0.y, q1.y, q2.y, q3.y)
        PN_TERM(s4.z, w4.z, q0.z, q1.z, q2.z, q3.z)
        PN_TERM(s4.w, w4.w, q0.w, q1.w, q2.w, q3.w)
        #undef PN_TERM
        s4 = nxt;
    }
    h2p[g][0][s] = acc0;
    h2p[g][1][s] = acc1;
    h2p[g][2][s] = acc2;
    h2p[g][3][s] = acc3;
    __syncthreads();

    if (tid < 256) {
        const int wv = tid >> 6, lane = tid & 63;
        float v0 = -2.0f * (h2p[0][wv][lane] + h2p[1][wv][lane]
                          + h2p[2][wv][lane] + h2p[3][wv][lane]);
        float v1 = -2.0f * (h2p[0][wv][lane + 64] + h2p[1][wv][lane + 64]
                          + h2p[2][wv][lane + 64] + h2p[3][wv][lane + 64]);
        if (mk0) v0 = -__builtin_inff();
        if (mk1) v1 = -__builtin_inff();

        float mx = fmaxf(v0, v1);
        #pragma unroll
        for (int off = 32; off >= 1; off >>= 1) mx = fmaxf(mx, __shfl_xor(mx, off));
        float e0 = fast_exp2((v0 - mx) * LOG2E);   // -inf -> 0
        float e1 = fast_exp2((v1 - mx) * LOG2E);
        float sum = e0 + e1;
        #pragma unroll
        for (int off = 32; off >= 1; off >>= 1) sum += __shfl_xor(sum, off);
        const float r = fast_rcp(sum);

        const size_t ob = (size_t)((tz * 4 + wv) * 32 + b) * 128;
        out[ob + lane]      = e0 * r;
        out[ob + lane + 64] = e1 * r;
    }
}

extern "C" void kernel_launch(void* const* d_in, const int* in_sizes, int n_in,
                              void* d_out, int out_size, void* d_ws, size_t ws_size,
                              hipStream_t stream) {
    const float* src   = (const float*)d_in[0];   // (B,S,E)
    const int*   mask  = (const int*)  d_in[1];   // (B,S)
    const float* query = (const float*)d_in[2];   // (T,B,Q)
    const float* W_src = (const float*)d_in[3];   // (H,E)
    const float* b_src = (const float*)d_in[4];
    const float* W_q   = (const float*)d_in[5];   // (H,Q)
    const float* b_q   = (const float*)d_in[6];
    const float* w2    = (const float*)d_in[7];
    // d_in[8] = b2 : unused (softmax shift-invariant)
    float* out = (float*)d_out;

    // ws: spq 4 MB @0 | qp 2 MB @4MB  (minimal footprint — ws is poisoned
    // with 256 MB of 0xAA every iteration; extra ws traffic is cold misses)
    float* spq = (float*)d_ws;
    float* qp  = (float*)((char*)d_ws + (4u << 20));

    proj_gemm<<<dim3(96, 4), 256, 0, stream>>>(src, query, W_src, W_q,
                                               b_src, b_q, spq, qp);
    attn_score<<<dim3(32, 16), 512, 0, stream>>>(spq, qp, w2, mask, out);
}